// Round 10
// baseline (578.981 us; speedup 1.0000x reference)
//
#include <hip/hip_runtime.h>

#define HIDDEN 512
#define BLK_ELEMS (64 * 128 * 8)   // elements per (128-row x 512-col) tiled block

typedef __attribute__((ext_vector_type(8))) short short8;
typedef __attribute__((ext_vector_type(4))) float f32x4;

__device__ __forceinline__ unsigned short f2bf(float f) {
    unsigned u = __float_as_uint(f);
    unsigned r = (u + 0x7FFFu + ((u >> 16) & 1u)) >> 16;
    return (unsigned short)r;
}
__device__ __forceinline__ float bf2f(unsigned short h) {
    return __uint_as_float(((unsigned)h) << 16);
}

__device__ __forceinline__ void load_lds16(const unsigned short* g, unsigned short* l) {
    __builtin_amdgcn_global_load_lds(
        (const __attribute__((address_space(1))) unsigned int*)(g),
        (__attribute__((address_space(3))) unsigned int*)(l), 16, 0, 0);
}

__device__ __forceinline__ void acc8(uint4 v, float cf, float* a) {
    a[0] = fmaf(cf, bf2f((unsigned short)(v.x & 0xFFFF)), a[0]);
    a[1] = fmaf(cf, bf2f((unsigned short)(v.x >> 16)),    a[1]);
    a[2] = fmaf(cf, bf2f((unsigned short)(v.y & 0xFFFF)), a[2]);
    a[3] = fmaf(cf, bf2f((unsigned short)(v.y >> 16)),    a[3]);
    a[4] = fmaf(cf, bf2f((unsigned short)(v.z & 0xFFFF)), a[4]);
    a[5] = fmaf(cf, bf2f((unsigned short)(v.z >> 16)),    a[5]);
    a[6] = fmaf(cf, bf2f((unsigned short)(v.w & 0xFFFF)), a[6]);
    a[7] = fmaf(cf, bf2f((unsigned short)(v.w >> 16)),    a[7]);
}

// ---------------- cast fp32 row-major -> tiled bf16 (per-chunk form; weights) ----------------
// tiled layout: [row/128][kchunk(64)][row%128][8 bf16]

__device__ __forceinline__ void cast_chunk(const float* __restrict__ src,
                                           unsigned short* __restrict__ dst,
                                           int rows, int o) {
    int blk = o >> 13;
    int rem = o & 8191;
    int g = rem >> 7;
    int m = rem & 127;
    int row = blk * 128 + m;
    short8 v;
    if (row < rows) {
        const float* p = src + (size_t)row * HIDDEN + g * 8;
        float4 f0 = *(const float4*)p;
        float4 f1 = *(const float4*)(p + 4);
        v[0] = (short)f2bf(f0.x); v[1] = (short)f2bf(f0.y);
        v[2] = (short)f2bf(f0.z); v[3] = (short)f2bf(f0.w);
        v[4] = (short)f2bf(f1.x); v[5] = (short)f2bf(f1.y);
        v[6] = (short)f2bf(f1.z); v[7] = (short)f2bf(f1.w);
    } else {
        v = (short8)0;
    }
    *(short8*)(dst + (size_t)o * 8) = v;
}

// ---------------- fused: edge-count | cast x (block-transpose, coalesced) ----------------

__global__ __launch_bounds__(256)
void fused_count_castx(const int* __restrict__ dstv, int* __restrict__ cnt, int E, int countB,
                       const float* __restrict__ x, unsigned short* __restrict__ bufA,
                       int rows, int nxb) {
    int b = blockIdx.x;
    if (b < countB) {
        int e = b * 256 + threadIdx.x;
        if (e < E) atomicAdd(&cnt[dstv[e]], 1);
        return;
    }
    int cb = b - countB;
    if (cb >= nxb) return;
    __shared__ __align__(16) unsigned short xs[32 * 520];   // 520 = 512 + 8 pad
    const int tid = threadIdx.x;
    const int r0 = cb * 32;
    #pragma unroll
    for (int p = 0; p < 16; ++p) {
        int f = p * 1024 + tid * 4;          // flat float index in [32][512]
        int rl = f >> 9;
        int col = f & 511;
        int grow = r0 + rl;
        uint2 w = make_uint2(0u, 0u);
        if (grow < rows) {
            float4 v = *(const float4*)(x + (size_t)grow * HIDDEN + col);
            w.x = (unsigned)f2bf(v.x) | ((unsigned)f2bf(v.y) << 16);
            w.y = (unsigned)f2bf(v.z) | ((unsigned)f2bf(v.w) << 16);
        }
        *(uint2*)(xs + rl * 520 + col) = w;
    }
    __syncthreads();
    const int blk = r0 >> 7;
    const int m0 = r0 & 127;
    unsigned short* dstb = bufA + (size_t)blk * BLK_ELEMS;
    #pragma unroll
    for (int p = 0; p < 8; ++p) {
        int c = p * 256 + tid;
        int g = c >> 5;
        int mloc = c & 31;
        short8 v = *(const short8*)(xs + mloc * 520 + g * 8);
        *(short8*)(dstb + g * 1024 + (m0 + mloc) * 8) = v;
    }
}

// ---------------- fused: per-block sums + norm | cast W1/W2/Wc ----------------

__global__ __launch_bounds__(256)
void fused_bsum_castw(const int* __restrict__ cnt, float* __restrict__ norm,
                      int* __restrict__ bsums, int n, int NSB,
                      const float* __restrict__ W1, const float* __restrict__ W2,
                      const float* __restrict__ Wc,
                      unsigned short* __restrict__ W1t, unsigned short* __restrict__ W2t,
                      unsigned short* __restrict__ Wct, int NC) {
    __shared__ int red[256];
    int tid = threadIdx.x;
    if ((int)blockIdx.x < NSB) {
        int i = blockIdx.x * 256 + tid;
        int v = 0;
        if (i < n) {
            v = cnt[i];
            norm[i] = rsqrtf((float)(v + 1));
        }
        red[tid] = v;
        __syncthreads();
        #pragma unroll
        for (int off = 128; off > 0; off >>= 1) {
            if (tid < off) red[tid] += red[tid + off];
            __syncthreads();
        }
        if (tid == 0) bsums[blockIdx.x] = red[0];
    } else {
        int o = ((int)blockIdx.x - NSB) * 256 + tid;
        if (o < 32768) {
            cast_chunk(W1, W1t, HIDDEN, o);
        } else if (o < 65536) {
            cast_chunk(W2, W2t, HIDDEN, o - 32768);
        } else if (o < 73728) {
            cast_chunk(Wc, Wct, NC, o - 65536);   // rows NC..127 zero-filled
        }
    }
}

// ---------------- scan: per-block rescan of bsums + element scan (proven R6) ----------------

__global__ __launch_bounds__(256)
void scan_final_kernel(const int* __restrict__ cnt, const int* __restrict__ bsums,
                       int* __restrict__ rowptr, int* __restrict__ cursor,
                       int n, int NSB) {
    __shared__ int buf[256];
    __shared__ int base;
    const int tid = threadIdx.x;
    const int b = blockIdx.x;
    int v = (tid < NSB) ? bsums[tid] : 0;
    buf[tid] = v;
    __syncthreads();
    #pragma unroll
    for (int off = 1; off < 256; off <<= 1) {
        int t = (tid >= off) ? buf[tid - off] : 0;
        __syncthreads();
        buf[tid] += t;
        __syncthreads();
    }
    if (tid == 0) base = (b > 0) ? buf[b - 1] : 0;
    if (b == 0 && tid == 0) rowptr[n] = buf[255];
    __syncthreads();
    int i = b * 256 + tid;
    int c = (i < n) ? cnt[i] : 0;
    buf[tid] = c;
    __syncthreads();
    #pragma unroll
    for (int off = 1; off < 256; off <<= 1) {
        int t = (tid >= off) ? buf[tid - off] : 0;
        __syncthreads();
        buf[tid] += t;
        __syncthreads();
    }
    if (i < n) {
        int ex = base + buf[tid] - c;
        rowptr[i] = ex;
        cursor[i] = ex;
    }
}

// ---------------- bf16 MFMA GEMM body (128x128 tile, C bf16 [M][512]) ----------------

__device__ __forceinline__ void gemm_body(const unsigned short* __restrict__ At,
                                          const unsigned short* __restrict__ Bt,
                                          void* __restrict__ Cout,
                                          int M, int mb, int nb) {
    __shared__ __align__(16) unsigned short As[8 * 128 * 8];  // 16 KB: [g][m][8]
    __shared__ __align__(16) unsigned short Bs[8 * 128 * 8];

    const int tid = threadIdx.x;
    const int wid = tid >> 6;
    const int lane = tid & 63;
    const int wm = wid & 1, wn = wid >> 1;
    const int lm = lane & 15;
    const int lq = lane >> 4;

    const unsigned short* Ab = At + (size_t)mb * BLK_ELEMS;
    const unsigned short* Bb = Bt + (size_t)nb * BLK_ELEMS;

    f32x4 acc[4][4];
    #pragma unroll
    for (int i = 0; i < 4; ++i)
        #pragma unroll
        for (int j = 0; j < 4; ++j) acc[i][j] = (f32x4)0.f;

    for (int kt = 0; kt < 8; ++kt) {
        __syncthreads();
        const unsigned short* ga = Ab + kt * (8 * 1024);
        const unsigned short* gb = Bb + kt * (8 * 1024);
        #pragma unroll
        for (int i = 0; i < 4; ++i) {
            int off = (tid + i * 256) * 8;
            load_lds16(ga + off, As + off);
            load_lds16(gb + off, Bs + off);
        }
        __syncthreads();
        #pragma unroll
        for (int ks = 0; ks < 2; ++ks) {
            int g = ks * 4 + lq;
            int base = g * 1024 + lm * 8;
            short8 af[4], bfr[4];
            #pragma unroll
            for (int mt = 0; mt < 4; ++mt)
                af[mt] = *(const short8*)&As[base + (wm * 64 + mt * 16) * 8];
            #pragma unroll
            for (int nt = 0; nt < 4; ++nt)
                bfr[nt] = *(const short8*)&Bs[base + (wn * 64 + nt * 16) * 8];
            #pragma unroll
            for (int mt = 0; mt < 4; ++mt)
                #pragma unroll
                for (int nt = 0; nt < 4; ++nt)
                    acc[mt][nt] = __builtin_amdgcn_mfma_f32_16x16x32_bf16(
                        af[mt], bfr[nt], acc[mt][nt], 0, 0, 0);
        }
    }

    #pragma unroll
    for (int mt = 0; mt < 4; ++mt) {
        #pragma unroll
        for (int nt = 0; nt < 4; ++nt) {
            int col = nb * 128 + wn * 64 + nt * 16 + lm;
            f32x4 v = acc[mt][nt];
            #pragma unroll
            for (int r = 0; r < 4; ++r) {
                int row = mb * 128 + wm * 64 + mt * 16 + lq * 4 + r;
                if (row < M)
                    ((unsigned short*)Cout)[(size_t)row * HIDDEN + col] = f2bf(v[r]);
            }
        }
    }
}

// XCD-grouped swizzle: 4 nb blocks of one mb land on one XCD back-to-back
__device__ __forceinline__ bool swz_decode(int bid, int NB, int& mb, int& nb) {
    int p = bid & 7;
    int s = bid >> 3;
    nb = s & 3;
    mb = (s >> 2) * 8 + p;
    return mb < NB;
}

__global__ __launch_bounds__(256)
void gemm_swz(const unsigned short* __restrict__ At, const unsigned short* __restrict__ Bt,
              void* __restrict__ Cout, int M, int NB) {
    int mb, nb;
    if (!swz_decode(blockIdx.x, NB, mb, nb)) return;
    gemm_body(At, Bt, Cout, M, mb, nb);
}

// ---------------- fused: CSR fill | gemm layer-1 ----------------

__global__ __launch_bounds__(256)
void fused_fill_gemm1(const int* __restrict__ src, const int* __restrict__ dstv,
                      const float* __restrict__ norm, int* __restrict__ cursor,
                      int2* __restrict__ epair, int E, int fillB,
                      const unsigned short* __restrict__ At, const unsigned short* __restrict__ Bt,
                      void* __restrict__ Cout, int M, int NB) {
    int b = blockIdx.x;
    if (b < fillB) {
        int e = b * 256 + threadIdx.x;
        if (e < E) {
            int s = src[e], d = dstv[e];
            float cf = norm[s] * norm[d];
            int p = atomicAdd(&cursor[d], 1);
            epair[p] = make_int2(s, __float_as_int(cf));
        }
    } else {
        int mb, nb;
        if (swz_decode(b - fillB, NB, mb, nb))
            gemm_body(At, Bt, Cout, M, mb, nb);
    }
}

// ---------------- aggregation #1: wave-per-node, 16 waves/block (R0 proven form) ----
// BW pinned at 3.7-4.1 TB/s across 3 concurrency configs (R0-R2) -> structural
// floor for the random-1KB-gather mix. Known poison: launch_bounds min-waves
// (R2: acc spilled, WRITE 454MB); nontemporal store (R7: write-combining broken,
// WRITE 65->157MB, +52us); wave-serial epilogue (R6: 675us).

__global__ __launch_bounds__(1024)
void aggregate_kernel(const unsigned short* __restrict__ h, const int* __restrict__ rowptr,
                      const int2* __restrict__ epair, const float* __restrict__ norm,
                      const float* __restrict__ bias, unsigned short* __restrict__ out_t,
                      int N) {
    const int wave = threadIdx.x >> 6;
    const int lane = threadIdx.x & 63;
    const int node = blockIdx.x * 16 + wave;
    if (node >= N) return;
    const uint4* h4 = (const uint4*)h;   // 64 chunks of 16B per row
    const int c = lane;

    float a[8];
    {
        uint4 sv = h4[(size_t)node * 64 + c];
        float nv = norm[node];
        float invd = nv * nv;
        a[0] = a[1] = a[2] = a[3] = a[4] = a[5] = a[6] = a[7] = 0.f;
        acc8(sv, invd, a);
    }

    int beg = rowptr[node], end = rowptr[node + 1];
    int j = beg;
    for (; j + 4 <= end; j += 4) {
        int2 p0 = epair[j + 0];
        int2 p1 = epair[j + 1];
        int2 p2 = epair[j + 2];
        int2 p3 = epair[j + 3];
        uint4 v0 = h4[(size_t)p0.x * 64 + c];
        uint4 v1 = h4[(size_t)p1.x * 64 + c];
        uint4 v2 = h4[(size_t)p2.x * 64 + c];
        uint4 v3 = h4[(size_t)p3.x * 64 + c];
        acc8(v0, __int_as_float(p0.y), a);
        acc8(v1, __int_as_float(p1.y), a);
        acc8(v2, __int_as_float(p2.y), a);
        acc8(v3, __int_as_float(p3.y), a);
    }
    for (; j < end; ++j) {
        int2 p = epair[j];
        uint4 v = h4[(size_t)p.x * 64 + c];
        acc8(v, __int_as_float(p.y), a);
    }

    const float4 b0 = *(const float4*)(bias + c * 8);
    const float4 b1 = *(const float4*)(bias + c * 8 + 4);
    a[0] = fmaxf(a[0] + b0.x, 0.f); a[1] = fmaxf(a[1] + b0.y, 0.f);
    a[2] = fmaxf(a[2] + b0.z, 0.f); a[3] = fmaxf(a[3] + b0.w, 0.f);
    a[4] = fmaxf(a[4] + b1.x, 0.f); a[5] = fmaxf(a[5] + b1.y, 0.f);
    a[6] = fmaxf(a[6] + b1.z, 0.f); a[7] = fmaxf(a[7] + b1.w, 0.f);

    size_t off = (size_t)(node >> 7) * BLK_ELEMS + (size_t)c * 1024 + (node & 127) * 8;
    uint4 o;
    o.x = (unsigned)f2bf(a[0]) | ((unsigned)f2bf(a[1]) << 16);
    o.y = (unsigned)f2bf(a[2]) | ((unsigned)f2bf(a[3]) << 16);
    o.z = (unsigned)f2bf(a[4]) | ((unsigned)f2bf(a[5]) << 16);
    o.w = (unsigned)f2bf(a[6]) | ((unsigned)f2bf(a[7]) << 16);
    *(uint4*)(out_t + off) = o;
}

// ---------------- aggregation #2 + MFMA classifier (proven R8) ----------------

__global__ __launch_bounds__(1024)
void aggregate_cls_mfma(const unsigned short* __restrict__ h, const int* __restrict__ rowptr,
                        const int2* __restrict__ epair, const float* __restrict__ norm,
                        const float* __restrict__ bias, const unsigned short* __restrict__ Wct,
                        const float* __restrict__ bc, float* __restrict__ out,
                        int N, int NC) {
    __shared__ __align__(16) unsigned short h2s[16 * 520];
    const int wave = threadIdx.x >> 6;
    const int lane = threadIdx.x & 63;
    const int node = blockIdx.x * 16 + wave;
    const uint4* h4 = (const uint4*)h;
    const int c = lane;

    float a[8];
    a[0] = a[1] = a[2] = a[3] = a[4] = a[5] = a[6] = a[7] = 0.f;
    if (node < N) {
        {
            uint4 sv = h4[(size_t)node * 64 + c];
            float nv = norm[node];
            acc8(sv, nv * nv, a);
        }
        int beg = rowptr[node], end = rowptr[node + 1];
        int j = beg;
        for (; j + 4 <= end; j += 4) {
            int2 p0 = epair[j + 0];
            int2 p1 = epair[j + 1];
            int2 p2 = epair[j + 2];
            int2 p3 = epair[j + 3];
            uint4 v0 = h4[(size_t)p0.x * 64 + c];
            uint4 v1 = h4[(size_t)p1.x * 64 + c];
            uint4 v2 = h4[(size_t)p2.x * 64 + c];
            uint4 v3 = h4[(size_t)p3.x * 64 + c];
            acc8(v0, __int_as_float(p0.y), a);
            acc8(v1, __int_as_float(p1.y), a);
            acc8(v2, __int_as_float(p2.y), a);
            acc8(v3, __int_as_float(p3.y), a);
        }
        for (; j < end; ++j) {
            int2 p = epair[j];
            uint4 v = h4[(size_t)p.x * 64 + c];
            acc8(v, __int_as_float(p.y), a);
        }
        const float4 b0 = *(const float4*)(bias + c * 8);
        const float4 b1 = *(const float4*)(bias + c * 8 + 4);
        a[0] = fmaxf(a[0] + b0.x, 0.f); a[1] = fmaxf(a[1] + b0.y, 0.f);
        a[2] = fmaxf(a[2] + b0.z, 0.f); a[3] = fmaxf(a[3] + b0.w, 0.f);
        a[4] = fmaxf(a[4] + b1.x, 0.f); a[5] = fmaxf(a[5] + b1.y, 0.f);
        a[6] = fmaxf(a[6] + b1.z, 0.f); a[7] = fmaxf(a[7] + b1.w, 0.f);
    }

    {
        short8 v;
        v[0] = (short)f2bf(a[0]); v[1] = (short)f2bf(a[1]);
        v[2] = (short)f2bf(a[2]); v[3] = (short)f2bf(a[3]);
        v[4] = (short)f2bf(a[4]); v[5] = (short)f2bf(a[5]);
        v[6] = (short)f2bf(a[6]); v[7] = (short)f2bf(a[7]);
        *(short8*)(h2s + wave * 520 + c * 8) = v;
    }
    __syncthreads();

    const int ct = wave;
    if (ct * 16 < NC) {
        const int lm = lane & 15;
        const int lq = lane >> 4;
        f32x4 acc = (f32x4)0.f;
        #pragma unroll
        for (int kk = 0; kk < 16; ++kk) {
            int g = kk * 4 + lq;                         // 8-elem k-chunk, 0..63
            short8 af = *(const short8*)&h2s[lm * 520 + g * 8];
            short8 bf = *(const short8*)&Wct[(size_t)g * 1024 + (ct * 16 + lm) * 8];
            acc = __builtin_amdgcn_mfma_f32_16x16x32_bf16(af, bf, acc, 0, 0, 0);
        }
        int col = ct * 16 + lm;
        if (col < NC) {
            float bcv = bc[col];
            #pragma unroll
            for (int r = 0; r < 4; ++r) {
                int row = lq * 4 + r;
                int gnode = blockIdx.x * 16 + row;
                if (gnode < N)
                    out[(size_t)gnode * NC + col] = acc[r] + bcv;
            }
        }
    }
}

// ---------------- launch ----------------
// R10 = R9 resubmit (R9 never ran: GPU acquisition timeout).
// INSTRUMENTATION ROUND: gemm_swz is launched 4x (idempotent: stable inputs,
// deterministic output -> bit-identical hbuf each time; correctness unaffected).
// delta_total = 3 x gemm2_dur + 3 x launch_gap resolves gemm2's true cost, which
// is invisible below the top-5 cutoff (87.7us). Bench noise is +-0.3us (R0 vs R1),
// so the measurement is clean. Decision: gemm2 ~25us -> GEMM lever dead, revert
// and declare near-roofline; gemm2 ~55-65us -> port deep-pipelined GEMM next.

extern "C" void kernel_launch(void* const* d_in, const int* in_sizes, int n_in,
                              void* d_out, int out_size, void* d_ws, size_t ws_size,
                              hipStream_t stream) {
    const float* x  = (const float*)d_in[0];
    const int*   ei = (const int*)d_in[1];
    const float* W1 = (const float*)d_in[2];
    const float* b1 = (const float*)d_in[3];
    const float* W2 = (const float*)d_in[4];
    const float* b2 = (const float*)d_in[5];
    const float* Wc = (const float*)d_in[6];
    const float* bc = (const float*)d_in[7];

    const int N  = in_sizes[0] / HIDDEN;      // 50000
    const int E  = in_sizes[1] / 2;           // 500000
    const int NC = in_sizes[6] / HIDDEN;      // 100
    const int NB = (N + 127) / 128;           // 391
    const int NSB = (N + 255) / 256;          // 196

    const int* src = ei;
    const int* dst = ei + E;

    char* ws = (char*)d_ws;
    int*   cnt    = (int*)(ws);
    int*   rowptr = (int*)(ws + (256 << 10));
    int*   cursor = (int*)(ws + (512 << 10));
    float* normv  = (float*)(ws + (768 << 10));
    int*   bsums  = (int*)(ws + (968 << 10));
    int2*  epair  = (int2*)(ws + (1ull << 20));                 // E*8 B = 4 MB
    unsigned short* W1t = (unsigned short*)(ws + (6ull << 20));
    unsigned short* W2t = (unsigned short*)(ws + (6ull << 20) + (512 << 10));
    unsigned short* Wct = (unsigned short*)(ws + (7ull << 20));
    unsigned short* bufA = (unsigned short*)(ws + (16ull << 20));
    unsigned short* bufB = (unsigned short*)(ws + (80ull << 20));
    unsigned short* hbuf = (unsigned short*)(ws + (144ull << 20));

    const int countB = (E + 255) / 256;                 // 1954
    const int nxb = NB * 4;                             // 1564 castx blocks (32 rows each)
    const int gemmB = 8 * 4 * ((NB + 7) / 8);           // 1568

    hipMemsetAsync(cnt, 0, N * sizeof(int), stream);
    // [edge count | cast x (block-transpose)]
    fused_count_castx<<<countB + nxb, 256, 0, stream>>>(dst, cnt, E, countB,
                                                        x, bufA, N, nxb);
    // [block sums + norm | cast W1/W2/Wc]
    fused_bsum_castw<<<NSB + 288, 256, 0, stream>>>(cnt, normv, bsums, N, NSB,
                                                    W1, W2, Wc, W1t, W2t, Wct, NC);
    // merged block-offset + element scan
    scan_final_kernel<<<NSB, 256, 0, stream>>>(cnt, bsums, rowptr, cursor, N, NSB);
    // [CSR fill | gemm layer-1]
    fused_fill_gemm1<<<countB + gemmB, 256, 0, stream>>>(src, dst, normv, cursor, epair,
                                                         E, countB,
                                                         bufA, W1t, hbuf, N, NB);
    const int aggB = (N + 15) / 16;
    aggregate_kernel<<<aggB, 1024, 0, stream>>>(hbuf, rowptr, epair, normv, b1, bufB, N);
    // gemm2 x4 (3 idempotent duplicates for timing; see comment above)
    gemm_swz<<<gemmB, 256, 0, stream>>>(bufB, W2t, hbuf, N, NB);
    gemm_swz<<<gemmB, 256, 0, stream>>>(bufB, W2t, hbuf, N, NB);
    gemm_swz<<<gemmB, 256, 0, stream>>>(bufB, W2t, hbuf, N, NB);
    gemm_swz<<<gemmB, 256, 0, stream>>>(bufB, W2t, hbuf, N, NB);
    // [aggregation 2 + MFMA classifier] -> d_out directly
    aggregate_cls_mfma<<<aggB, 1024, 0, stream>>>(hbuf, rowptr, epair, normv, b2,
                                                  Wct, bc, (float*)d_out, N, NC);
}

// Round 11
// 484.768 us; speedup vs baseline: 1.1943x; 1.1943x over previous
//
#include <hip/hip_runtime.h>

#define HIDDEN 512
#define BLK_ELEMS (64 * 128 * 8)   // elements per (128-row x 512-col) tiled block

typedef __attribute__((ext_vector_type(8))) short short8;
typedef __attribute__((ext_vector_type(4))) float f32x4;

__device__ __forceinline__ unsigned short f2bf(float f) {
    unsigned u = __float_as_uint(f);
    unsigned r = (u + 0x7FFFu + ((u >> 16) & 1u)) >> 16;
    return (unsigned short)r;
}
__device__ __forceinline__ float bf2f(unsigned short h) {
    return __uint_as_float(((unsigned)h) << 16);
}

__device__ __forceinline__ void load_lds16(const unsigned short* g, unsigned short* l) {
    __builtin_amdgcn_global_load_lds(
        (const __attribute__((address_space(1))) unsigned int*)(g),
        (__attribute__((address_space(3))) unsigned int*)(l), 16, 0, 0);
}

__device__ __forceinline__ void acc8(uint4 v, float cf, float* a) {
    a[0] = fmaf(cf, bf2f((unsigned short)(v.x & 0xFFFF)), a[0]);
    a[1] = fmaf(cf, bf2f((unsigned short)(v.x >> 16)),    a[1]);
    a[2] = fmaf(cf, bf2f((unsigned short)(v.y & 0xFFFF)), a[2]);
    a[3] = fmaf(cf, bf2f((unsigned short)(v.y >> 16)),    a[3]);
    a[4] = fmaf(cf, bf2f((unsigned short)(v.z & 0xFFFF)), a[4]);
    a[5] = fmaf(cf, bf2f((unsigned short)(v.z >> 16)),    a[5]);
    a[6] = fmaf(cf, bf2f((unsigned short)(v.w & 0xFFFF)), a[6]);
    a[7] = fmaf(cf, bf2f((unsigned short)(v.w >> 16)),    a[7]);
}

// ---------------- cast fp32 row-major -> tiled bf16 (per-chunk form; weights) ----------------
// tiled layout: [row/128][kchunk(64)][row%128][8 bf16]

__device__ __forceinline__ void cast_chunk(const float* __restrict__ src,
                                           unsigned short* __restrict__ dst,
                                           int rows, int o) {
    int blk = o >> 13;
    int rem = o & 8191;
    int g = rem >> 7;
    int m = rem & 127;
    int row = blk * 128 + m;
    short8 v;
    if (row < rows) {
        const float* p = src + (size_t)row * HIDDEN + g * 8;
        float4 f0 = *(const float4*)p;
        float4 f1 = *(const float4*)(p + 4);
        v[0] = (short)f2bf(f0.x); v[1] = (short)f2bf(f0.y);
        v[2] = (short)f2bf(f0.z); v[3] = (short)f2bf(f0.w);
        v[4] = (short)f2bf(f1.x); v[5] = (short)f2bf(f1.y);
        v[6] = (short)f2bf(f1.z); v[7] = (short)f2bf(f1.w);
    } else {
        v = (short8)0;
    }
    *(short8*)(dst + (size_t)o * 8) = v;
}

// ---------------- fused: edge-count | cast x (block-transpose, coalesced) ----------------

__global__ __launch_bounds__(256)
void fused_count_castx(const int* __restrict__ dstv, int* __restrict__ cnt, int E, int countB,
                       const float* __restrict__ x, unsigned short* __restrict__ bufA,
                       int rows, int nxb) {
    int b = blockIdx.x;
    if (b < countB) {
        int e = b * 256 + threadIdx.x;
        if (e < E) atomicAdd(&cnt[dstv[e]], 1);
        return;
    }
    int cb = b - countB;
    if (cb >= nxb) return;
    __shared__ __align__(16) unsigned short xs[32 * 520];   // 520 = 512 + 8 pad
    const int tid = threadIdx.x;
    const int r0 = cb * 32;
    #pragma unroll
    for (int p = 0; p < 16; ++p) {
        int f = p * 1024 + tid * 4;          // flat float index in [32][512]
        int rl = f >> 9;
        int col = f & 511;
        int grow = r0 + rl;
        uint2 w = make_uint2(0u, 0u);
        if (grow < rows) {
            float4 v = *(const float4*)(x + (size_t)grow * HIDDEN + col);
            w.x = (unsigned)f2bf(v.x) | ((unsigned)f2bf(v.y) << 16);
            w.y = (unsigned)f2bf(v.z) | ((unsigned)f2bf(v.w) << 16);
        }
        *(uint2*)(xs + rl * 520 + col) = w;
    }
    __syncthreads();
    const int blk = r0 >> 7;
    const int m0 = r0 & 127;
    unsigned short* dstb = bufA + (size_t)blk * BLK_ELEMS;
    #pragma unroll
    for (int p = 0; p < 8; ++p) {
        int c = p * 256 + tid;
        int g = c >> 5;
        int mloc = c & 31;
        short8 v = *(const short8*)(xs + mloc * 520 + g * 8);
        *(short8*)(dstb + g * 1024 + (m0 + mloc) * 8) = v;
    }
}

// ---------------- fused: norm + direct full scan | cast W1/W2/Wc ----------------
// R11: scan_final_kernel eliminated. NSB=196 and cnt is L2-hot, so each scan
// block directly sums cnt[0 .. b*256) for its exclusive base (worst block reads
// 50K ints ~ 0.6us; 19.6MB total L2 traffic) then scans its own 256-segment.
// Removes the bsums/bscan handshake and one launch (8 -> 7).

__global__ __launch_bounds__(256)
void fused_scan_castw(const int* __restrict__ cnt, float* __restrict__ norm,
                      int* __restrict__ rowptr, int* __restrict__ cursor,
                      int n, int NSB,
                      const float* __restrict__ W1, const float* __restrict__ W2,
                      const float* __restrict__ Wc,
                      unsigned short* __restrict__ W1t, unsigned short* __restrict__ W2t,
                      unsigned short* __restrict__ Wct, int NC) {
    const int tid = threadIdx.x;
    const int b = blockIdx.x;
    if (b < NSB) {
        __shared__ int buf[256];
        __shared__ int sbase;
        // exclusive base: sum of cnt[0 .. b*256)
        const int lim = b * 256;
        int s = 0;
        for (int i = tid; i < lim; i += 256) s += cnt[i];
        buf[tid] = s;
        __syncthreads();
        #pragma unroll
        for (int off = 128; off > 0; off >>= 1) {
            if (tid < off) buf[tid] += buf[tid + off];
            __syncthreads();
        }
        if (tid == 0) sbase = buf[0];
        __syncthreads();
        const int base = sbase;
        // own value + norm
        int i = lim + tid;
        int v = 0;
        if (i < n) {
            v = cnt[i];
            norm[i] = rsqrtf((float)(v + 1));
        }
        __syncthreads();              // done with buf as reduce scratch
        buf[tid] = v;
        __syncthreads();
        #pragma unroll
        for (int off = 1; off < 256; off <<= 1) {
            int t = (tid >= off) ? buf[tid - off] : 0;
            __syncthreads();
            buf[tid] += t;
            __syncthreads();
        }
        if (i < n) {
            int ex = base + buf[tid] - v;
            rowptr[i] = ex;
            cursor[i] = ex;
        }
        if (b == NSB - 1 && tid == 255) rowptr[n] = base + buf[255];  // total E
    } else {
        int o = (b - NSB) * 256 + tid;
        if (o < 32768) {
            cast_chunk(W1, W1t, HIDDEN, o);
        } else if (o < 65536) {
            cast_chunk(W2, W2t, HIDDEN, o - 32768);
        } else if (o < 73728) {
            cast_chunk(Wc, Wct, NC, o - 65536);   // rows NC..127 zero-filled
        }
    }
}

// ---------------- bf16 MFMA GEMM body (128x128 tile, C bf16 [M][512]) ----------------

__device__ __forceinline__ void gemm_body(const unsigned short* __restrict__ At,
                                          const unsigned short* __restrict__ Bt,
                                          void* __restrict__ Cout,
                                          int M, int mb, int nb) {
    __shared__ __align__(16) unsigned short As[8 * 128 * 8];  // 16 KB: [g][m][8]
    __shared__ __align__(16) unsigned short Bs[8 * 128 * 8];

    const int tid = threadIdx.x;
    const int wid = tid >> 6;
    const int lane = tid & 63;
    const int wm = wid & 1, wn = wid >> 1;
    const int lm = lane & 15;
    const int lq = lane >> 4;

    const unsigned short* Ab = At + (size_t)mb * BLK_ELEMS;
    const unsigned short* Bb = Bt + (size_t)nb * BLK_ELEMS;

    f32x4 acc[4][4];
    #pragma unroll
    for (int i = 0; i < 4; ++i)
        #pragma unroll
        for (int j = 0; j < 4; ++j) acc[i][j] = (f32x4)0.f;

    for (int kt = 0; kt < 8; ++kt) {
        __syncthreads();
        const unsigned short* ga = Ab + kt * (8 * 1024);
        const unsigned short* gb = Bb + kt * (8 * 1024);
        #pragma unroll
        for (int i = 0; i < 4; ++i) {
            int off = (tid + i * 256) * 8;
            load_lds16(ga + off, As + off);
            load_lds16(gb + off, Bs + off);
        }
        __syncthreads();
        #pragma unroll
        for (int ks = 0; ks < 2; ++ks) {
            int g = ks * 4 + lq;
            int base = g * 1024 + lm * 8;
            short8 af[4], bfr[4];
            #pragma unroll
            for (int mt = 0; mt < 4; ++mt)
                af[mt] = *(const short8*)&As[base + (wm * 64 + mt * 16) * 8];
            #pragma unroll
            for (int nt = 0; nt < 4; ++nt)
                bfr[nt] = *(const short8*)&Bs[base + (wn * 64 + nt * 16) * 8];
            #pragma unroll
            for (int mt = 0; mt < 4; ++mt)
                #pragma unroll
                for (int nt = 0; nt < 4; ++nt)
                    acc[mt][nt] = __builtin_amdgcn_mfma_f32_16x16x32_bf16(
                        af[mt], bfr[nt], acc[mt][nt], 0, 0, 0);
        }
    }

    #pragma unroll
    for (int mt = 0; mt < 4; ++mt) {
        #pragma unroll
        for (int nt = 0; nt < 4; ++nt) {
            int col = nb * 128 + wn * 64 + nt * 16 + lm;
            f32x4 v = acc[mt][nt];
            #pragma unroll
            for (int r = 0; r < 4; ++r) {
                int row = mb * 128 + wm * 64 + mt * 16 + lq * 4 + r;
                if (row < M)
                    ((unsigned short*)Cout)[(size_t)row * HIDDEN + col] = f2bf(v[r]);
            }
        }
    }
}

// XCD-grouped swizzle: 4 nb blocks of one mb land on one XCD back-to-back
__device__ __forceinline__ bool swz_decode(int bid, int NB, int& mb, int& nb) {
    int p = bid & 7;
    int s = bid >> 3;
    nb = s & 3;
    mb = (s >> 2) * 8 + p;
    return mb < NB;
}

__global__ __launch_bounds__(256)
void gemm_swz(const unsigned short* __restrict__ At, const unsigned short* __restrict__ Bt,
              void* __restrict__ Cout, int M, int NB) {
    int mb, nb;
    if (!swz_decode(blockIdx.x, NB, mb, nb)) return;
    gemm_body(At, Bt, Cout, M, mb, nb);
}

// ---------------- fused: CSR fill | gemm layer-1 ----------------

__global__ __launch_bounds__(256)
void fused_fill_gemm1(const int* __restrict__ src, const int* __restrict__ dstv,
                      const float* __restrict__ norm, int* __restrict__ cursor,
                      int2* __restrict__ epair, int E, int fillB,
                      const unsigned short* __restrict__ At, const unsigned short* __restrict__ Bt,
                      void* __restrict__ Cout, int M, int NB) {
    int b = blockIdx.x;
    if (b < fillB) {
        int e = b * 256 + threadIdx.x;
        if (e < E) {
            int s = src[e], d = dstv[e];
            float cf = norm[s] * norm[d];
            int p = atomicAdd(&cursor[d], 1);
            epair[p] = make_int2(s, __float_as_int(cf));
        }
    } else {
        int mb, nb;
        if (swz_decode(b - fillB, NB, mb, nb))
            gemm_body(At, Bt, Cout, M, mb, nb);
    }
}

// ---------------- aggregation #1: wave-per-node, 16 waves/block (R0 proven form) ----
// BW pinned at 3.7-4.1 TB/s across 3 concurrency configs (R0-R2) -> structural
// floor for the random-1KB-gather mix. Known poison: launch_bounds min-waves
// (R2: acc spilled, WRITE 454MB); nontemporal store (R7: write-combining broken,
// WRITE 65->157MB, +52us); wave-serial epilogue (R6: 675us).

__global__ __launch_bounds__(1024)
void aggregate_kernel(const unsigned short* __restrict__ h, const int* __restrict__ rowptr,
                      const int2* __restrict__ epair, const float* __restrict__ norm,
                      const float* __restrict__ bias, unsigned short* __restrict__ out_t,
                      int N) {
    const int wave = threadIdx.x >> 6;
    const int lane = threadIdx.x & 63;
    const int node = blockIdx.x * 16 + wave;
    if (node >= N) return;
    const uint4* h4 = (const uint4*)h;   // 64 chunks of 16B per row
    const int c = lane;

    float a[8];
    {
        uint4 sv = h4[(size_t)node * 64 + c];
        float nv = norm[node];
        float invd = nv * nv;
        a[0] = a[1] = a[2] = a[3] = a[4] = a[5] = a[6] = a[7] = 0.f;
        acc8(sv, invd, a);
    }

    int beg = rowptr[node], end = rowptr[node + 1];
    int j = beg;
    for (; j + 4 <= end; j += 4) {
        int2 p0 = epair[j + 0];
        int2 p1 = epair[j + 1];
        int2 p2 = epair[j + 2];
        int2 p3 = epair[j + 3];
        uint4 v0 = h4[(size_t)p0.x * 64 + c];
        uint4 v1 = h4[(size_t)p1.x * 64 + c];
        uint4 v2 = h4[(size_t)p2.x * 64 + c];
        uint4 v3 = h4[(size_t)p3.x * 64 + c];
        acc8(v0, __int_as_float(p0.y), a);
        acc8(v1, __int_as_float(p1.y), a);
        acc8(v2, __int_as_float(p2.y), a);
        acc8(v3, __int_as_float(p3.y), a);
    }
    for (; j < end; ++j) {
        int2 p = epair[j];
        uint4 v = h4[(size_t)p.x * 64 + c];
        acc8(v, __int_as_float(p.y), a);
    }

    const float4 b0 = *(const float4*)(bias + c * 8);
    const float4 b1 = *(const float4*)(bias + c * 8 + 4);
    a[0] = fmaxf(a[0] + b0.x, 0.f); a[1] = fmaxf(a[1] + b0.y, 0.f);
    a[2] = fmaxf(a[2] + b0.z, 0.f); a[3] = fmaxf(a[3] + b0.w, 0.f);
    a[4] = fmaxf(a[4] + b1.x, 0.f); a[5] = fmaxf(a[5] + b1.y, 0.f);
    a[6] = fmaxf(a[6] + b1.z, 0.f); a[7] = fmaxf(a[7] + b1.w, 0.f);

    size_t off = (size_t)(node >> 7) * BLK_ELEMS + (size_t)c * 1024 + (node & 127) * 8;
    uint4 o;
    o.x = (unsigned)f2bf(a[0]) | ((unsigned)f2bf(a[1]) << 16);
    o.y = (unsigned)f2bf(a[2]) | ((unsigned)f2bf(a[3]) << 16);
    o.z = (unsigned)f2bf(a[4]) | ((unsigned)f2bf(a[5]) << 16);
    o.w = (unsigned)f2bf(a[6]) | ((unsigned)f2bf(a[7]) << 16);
    *(uint4*)(out_t + off) = o;
}

// ---------------- aggregation #2 + MFMA classifier (proven R8) ----------------

__global__ __launch_bounds__(1024)
void aggregate_cls_mfma(const unsigned short* __restrict__ h, const int* __restrict__ rowptr,
                        const int2* __restrict__ epair, const float* __restrict__ norm,
                        const float* __restrict__ bias, const unsigned short* __restrict__ Wct,
                        const float* __restrict__ bc, float* __restrict__ out,
                        int N, int NC) {
    __shared__ __align__(16) unsigned short h2s[16 * 520];
    const int wave = threadIdx.x >> 6;
    const int lane = threadIdx.x & 63;
    const int node = blockIdx.x * 16 + wave;
    const uint4* h4 = (const uint4*)h;
    const int c = lane;

    float a[8];
    a[0] = a[1] = a[2] = a[3] = a[4] = a[5] = a[6] = a[7] = 0.f;
    if (node < N) {
        {
            uint4 sv = h4[(size_t)node * 64 + c];
            float nv = norm[node];
            acc8(sv, nv * nv, a);
        }
        int beg = rowptr[node], end = rowptr[node + 1];
        int j = beg;
        for (; j + 4 <= end; j += 4) {
            int2 p0 = epair[j + 0];
            int2 p1 = epair[j + 1];
            int2 p2 = epair[j + 2];
            int2 p3 = epair[j + 3];
            uint4 v0 = h4[(size_t)p0.x * 64 + c];
            uint4 v1 = h4[(size_t)p1.x * 64 + c];
            uint4 v2 = h4[(size_t)p2.x * 64 + c];
            uint4 v3 = h4[(size_t)p3.x * 64 + c];
            acc8(v0, __int_as_float(p0.y), a);
            acc8(v1, __int_as_float(p1.y), a);
            acc8(v2, __int_as_float(p2.y), a);
            acc8(v3, __int_as_float(p3.y), a);
        }
        for (; j < end; ++j) {
            int2 p = epair[j];
            uint4 v = h4[(size_t)p.x * 64 + c];
            acc8(v, __int_as_float(p.y), a);
        }
        const float4 b0 = *(const float4*)(bias + c * 8);
        const float4 b1 = *(const float4*)(bias + c * 8 + 4);
        a[0] = fmaxf(a[0] + b0.x, 0.f); a[1] = fmaxf(a[1] + b0.y, 0.f);
        a[2] = fmaxf(a[2] + b0.z, 0.f); a[3] = fmaxf(a[3] + b0.w, 0.f);
        a[4] = fmaxf(a[4] + b1.x, 0.f); a[5] = fmaxf(a[5] + b1.y, 0.f);
        a[6] = fmaxf(a[6] + b1.z, 0.f); a[7] = fmaxf(a[7] + b1.w, 0.f);
    }

    {
        short8 v;
        v[0] = (short)f2bf(a[0]); v[1] = (short)f2bf(a[1]);
        v[2] = (short)f2bf(a[2]); v[3] = (short)f2bf(a[3]);
        v[4] = (short)f2bf(a[4]); v[5] = (short)f2bf(a[5]);
        v[6] = (short)f2bf(a[6]); v[7] = (short)f2bf(a[7]);
        *(short8*)(h2s + wave * 520 + c * 8) = v;
    }
    __syncthreads();

    const int ct = wave;
    if (ct * 16 < NC) {
        const int lm = lane & 15;
        const int lq = lane >> 4;
        f32x4 acc = (f32x4)0.f;
        #pragma unroll
        for (int kk = 0; kk < 16; ++kk) {
            int g = kk * 4 + lq;                         // 8-elem k-chunk, 0..63
            short8 af = *(const short8*)&h2s[lm * 520 + g * 8];
            short8 bf = *(const short8*)&Wct[(size_t)g * 1024 + (ct * 16 + lm) * 8];
            acc = __builtin_amdgcn_mfma_f32_16x16x32_bf16(af, bf, acc, 0, 0, 0);
        }
        int col = ct * 16 + lm;
        if (col < NC) {
            float bcv = bc[col];
            #pragma unroll
            for (int r = 0; r < 4; ++r) {
                int row = lq * 4 + r;
                int gnode = blockIdx.x * 16 + row;
                if (gnode < N)
                    out[(size_t)gnode * NC + col] = acc[r] + bcv;
            }
        }
    }
}

// ---------------- launch ----------------
// R11: revert to single gemm2 (R10 measured gemm2+gap ~ 37us -> ~770 TF, near
// the 128^2-structure ceiling for K=512; 8-phase port upside ~10us/GEMM vs
// demonstrated regression risk -> GEMM lever closed). Merge scan into castw
// kernel (7 launches). If the scan merge saves >=12us, launch gaps are large ->
// pursue deeper fusion; if <=8us, pipeline is at structural floor -> declare.

extern "C" void kernel_launch(void* const* d_in, const int* in_sizes, int n_in,
                              void* d_out, int out_size, void* d_ws, size_t ws_size,
                              hipStream_t stream) {
    const float* x  = (const float*)d_in[0];
    const int*   ei = (const int*)d_in[1];
    const float* W1 = (const float*)d_in[2];
    const float* b1 = (const float*)d_in[3];
    const float* W2 = (const float*)d_in[4];
    const float* b2 = (const float*)d_in[5];
    const float* Wc = (const float*)d_in[6];
    const float* bc = (const float*)d_in[7];

    const int N  = in_sizes[0] / HIDDEN;      // 50000
    const int E  = in_sizes[1] / 2;           // 500000
    const int NC = in_sizes[6] / HIDDEN;      // 100
    const int NB = (N + 127) / 128;           // 391
    const int NSB = (N + 255) / 256;          // 196

    const int* src = ei;
    const int* dst = ei + E;

    char* ws = (char*)d_ws;
    int*   cnt    = (int*)(ws);
    int*   rowptr = (int*)(ws + (256 << 10));
    int*   cursor = (int*)(ws + (512 << 10));
    float* normv  = (float*)(ws + (768 << 10));
    int2*  epair  = (int2*)(ws + (1ull << 20));                 // E*8 B = 4 MB
    unsigned short* W1t = (unsigned short*)(ws + (6ull << 20));
    unsigned short* W2t = (unsigned short*)(ws + (6ull << 20) + (512 << 10));
    unsigned short* Wct = (unsigned short*)(ws + (7ull << 20));
    unsigned short* bufA = (unsigned short*)(ws + (16ull << 20));
    unsigned short* bufB = (unsigned short*)(ws + (80ull << 20));
    unsigned short* hbuf = (unsigned short*)(ws + (144ull << 20));

    const int countB = (E + 255) / 256;                 // 1954
    const int nxb = NB * 4;                             // 1564 castx blocks (32 rows each)
    const int gemmB = 8 * 4 * ((NB + 7) / 8);           // 1568

    hipMemsetAsync(cnt, 0, N * sizeof(int), stream);
    // [edge count | cast x (block-transpose)]
    fused_count_castx<<<countB + nxb, 256, 0, stream>>>(dst, cnt, E, countB,
                                                        x, bufA, N, nxb);
    // [norm + direct full scan | cast W1/W2/Wc] (bsum/bscan handshake eliminated)
    fused_scan_castw<<<NSB + 288, 256, 0, stream>>>(cnt, normv, rowptr, cursor, N, NSB,
                                                    W1, W2, Wc, W1t, W2t, Wct, NC);
    // [CSR fill | gemm layer-1]
    fused_fill_gemm1<<<countB + gemmB, 256, 0, stream>>>(src, dst, normv, cursor, epair,
                                                         E, countB,
                                                         bufA, W1t, hbuf, N, NB);
    const int aggB = (N + 15) / 16;
    aggregate_kernel<<<aggB, 1024, 0, stream>>>(hbuf, rowptr, epair, normv, b1, bufB, N);
    gemm_swz<<<gemmB, 256, 0, stream>>>(bufB, W2t, hbuf, N, NB);
    // [aggregation 2 + MFMA classifier] -> d_out directly
    aggregate_cls_mfma<<<aggB, 1024, 0, stream>>>(hbuf, rowptr, epair, normv, b2,
                                                  Wct, bc, (float*)d_out, N, NC);
}

// Round 12
// 464.728 us; speedup vs baseline: 1.2458x; 1.0431x over previous
//
#include <hip/hip_runtime.h>

#define HIDDEN 512
#define BLK_ELEMS (64 * 128 * 8)   // elements per (128-row x 512-col) tiled block

typedef __attribute__((ext_vector_type(8))) short short8;
typedef __attribute__((ext_vector_type(4))) float f32x4;

__device__ __forceinline__ unsigned short f2bf(float f) {
    unsigned u = __float_as_uint(f);
    unsigned r = (u + 0x7FFFu + ((u >> 16) & 1u)) >> 16;
    return (unsigned short)r;
}
__device__ __forceinline__ float bf2f(unsigned short h) {
    return __uint_as_float(((unsigned)h) << 16);
}

__device__ __forceinline__ void load_lds16(const unsigned short* g, unsigned short* l) {
    __builtin_amdgcn_global_load_lds(
        (const __attribute__((address_space(1))) unsigned int*)(g),
        (__attribute__((address_space(3))) unsigned int*)(l), 16, 0, 0);
}

__device__ __forceinline__ void acc8(uint4 v, float cf, float* a) {
    a[0] = fmaf(cf, bf2f((unsigned short)(v.x & 0xFFFF)), a[0]);
    a[1] = fmaf(cf, bf2f((unsigned short)(v.x >> 16)),    a[1]);
    a[2] = fmaf(cf, bf2f((unsigned short)(v.y & 0xFFFF)), a[2]);
    a[3] = fmaf(cf, bf2f((unsigned short)(v.y >> 16)),    a[3]);
    a[4] = fmaf(cf, bf2f((unsigned short)(v.z & 0xFFFF)), a[4]);
    a[5] = fmaf(cf, bf2f((unsigned short)(v.z >> 16)),    a[5]);
    a[6] = fmaf(cf, bf2f((unsigned short)(v.w & 0xFFFF)), a[6]);
    a[7] = fmaf(cf, bf2f((unsigned short)(v.w >> 16)),    a[7]);
}

// ---------------- cast fp32 row-major -> tiled bf16 (per-chunk form; weights) ----------------
// tiled layout: [row/128][kchunk(64)][row%128][8 bf16]

__device__ __forceinline__ void cast_chunk(const float* __restrict__ src,
                                           unsigned short* __restrict__ dst,
                                           int rows, int o) {
    int blk = o >> 13;
    int rem = o & 8191;
    int g = rem >> 7;
    int m = rem & 127;
    int row = blk * 128 + m;
    short8 v;
    if (row < rows) {
        const float* p = src + (size_t)row * HIDDEN + g * 8;
        float4 f0 = *(const float4*)p;
        float4 f1 = *(const float4*)(p + 4);
        v[0] = (short)f2bf(f0.x); v[1] = (short)f2bf(f0.y);
        v[2] = (short)f2bf(f0.z); v[3] = (short)f2bf(f0.w);
        v[4] = (short)f2bf(f1.x); v[5] = (short)f2bf(f1.y);
        v[6] = (short)f2bf(f1.z); v[7] = (short)f2bf(f1.w);
    } else {
        v = (short8)0;
    }
    *(short8*)(dst + (size_t)o * 8) = v;
}

// ---------------- fused: edge-count | cast x (block-transpose, coalesced) ----------------

__global__ __launch_bounds__(256)
void fused_count_castx(const int* __restrict__ dstv, int* __restrict__ cnt, int E, int countB,
                       const float* __restrict__ x, unsigned short* __restrict__ bufA,
                       int rows, int nxb) {
    int b = blockIdx.x;
    if (b < countB) {
        int e = b * 256 + threadIdx.x;
        if (e < E) atomicAdd(&cnt[dstv[e]], 1);
        return;
    }
    int cb = b - countB;
    if (cb >= nxb) return;
    __shared__ __align__(16) unsigned short xs[32 * 520];   // 520 = 512 + 8 pad
    const int tid = threadIdx.x;
    const int r0 = cb * 32;
    #pragma unroll
    for (int p = 0; p < 16; ++p) {
        int f = p * 1024 + tid * 4;          // flat float index in [32][512]
        int rl = f >> 9;
        int col = f & 511;
        int grow = r0 + rl;
        uint2 w = make_uint2(0u, 0u);
        if (grow < rows) {
            float4 v = *(const float4*)(x + (size_t)grow * HIDDEN + col);
            w.x = (unsigned)f2bf(v.x) | ((unsigned)f2bf(v.y) << 16);
            w.y = (unsigned)f2bf(v.z) | ((unsigned)f2bf(v.w) << 16);
        }
        *(uint2*)(xs + rl * 520 + col) = w;
    }
    __syncthreads();
    const int blk = r0 >> 7;
    const int m0 = r0 & 127;
    unsigned short* dstb = bufA + (size_t)blk * BLK_ELEMS;
    #pragma unroll
    for (int p = 0; p < 8; ++p) {
        int c = p * 256 + tid;
        int g = c >> 5;
        int mloc = c & 31;
        short8 v = *(const short8*)(xs + mloc * 520 + g * 8);
        *(short8*)(dstb + g * 1024 + (m0 + mloc) * 8) = v;
    }
}

// ---------------- fused: per-block sums + norm | cast W1/W2/Wc ----------------

__global__ __launch_bounds__(256)
void fused_bsum_castw(const int* __restrict__ cnt, float* __restrict__ norm,
                      int* __restrict__ bsums, int n, int NSB,
                      const float* __restrict__ W1, const float* __restrict__ W2,
                      const float* __restrict__ Wc,
                      unsigned short* __restrict__ W1t, unsigned short* __restrict__ W2t,
                      unsigned short* __restrict__ Wct, int NC) {
    __shared__ int red[256];
    int tid = threadIdx.x;
    if ((int)blockIdx.x < NSB) {
        int i = blockIdx.x * 256 + tid;
        int v = 0;
        if (i < n) {
            v = cnt[i];
            norm[i] = rsqrtf((float)(v + 1));
        }
        red[tid] = v;
        __syncthreads();
        #pragma unroll
        for (int off = 128; off > 0; off >>= 1) {
            if (tid < off) red[tid] += red[tid + off];
            __syncthreads();
        }
        if (tid == 0) bsums[blockIdx.x] = red[0];
    } else {
        int o = ((int)blockIdx.x - NSB) * 256 + tid;
        if (o < 32768) {
            cast_chunk(W1, W1t, HIDDEN, o);
        } else if (o < 65536) {
            cast_chunk(W2, W2t, HIDDEN, o - 32768);
        } else if (o < 73728) {
            cast_chunk(Wc, Wct, NC, o - 65536);   // rows NC..127 zero-filled
        }
    }
}

// ---------------- scan: per-block rescan of bsums + element scan (proven R6/R8) ----------------
// Do NOT replace with direct per-block prefix over cnt (R11: runtime-trip-count
// latency chain, ~195 iter x ~200cyc L2 = +17us; bsums rescan is 1 iteration).

__global__ __launch_bounds__(256)
void scan_final_kernel(const int* __restrict__ cnt, const int* __restrict__ bsums,
                       int* __restrict__ rowptr, int* __restrict__ cursor,
                       int n, int NSB) {
    __shared__ int buf[256];
    __shared__ int base;
    const int tid = threadIdx.x;
    const int b = blockIdx.x;
    int v = (tid < NSB) ? bsums[tid] : 0;
    buf[tid] = v;
    __syncthreads();
    #pragma unroll
    for (int off = 1; off < 256; off <<= 1) {
        int t = (tid >= off) ? buf[tid - off] : 0;
        __syncthreads();
        buf[tid] += t;
        __syncthreads();
    }
    if (tid == 0) base = (b > 0) ? buf[b - 1] : 0;
    if (b == 0 && tid == 0) rowptr[n] = buf[255];
    __syncthreads();
    int i = b * 256 + tid;
    int c = (i < n) ? cnt[i] : 0;
    buf[tid] = c;
    __syncthreads();
    #pragma unroll
    for (int off = 1; off < 256; off <<= 1) {
        int t = (tid >= off) ? buf[tid - off] : 0;
        __syncthreads();
        buf[tid] += t;
        __syncthreads();
    }
    if (i < n) {
        int ex = base + buf[tid] - c;
        rowptr[i] = ex;
        cursor[i] = ex;
    }
}

// ---------------- bf16 MFMA GEMM body (128x128 tile, C bf16 [M][512]) ----------------

__device__ __forceinline__ void gemm_body(const unsigned short* __restrict__ At,
                                          const unsigned short* __restrict__ Bt,
                                          void* __restrict__ Cout,
                                          int M, int mb, int nb) {
    __shared__ __align__(16) unsigned short As[8 * 128 * 8];  // 16 KB: [g][m][8]
    __shared__ __align__(16) unsigned short Bs[8 * 128 * 8];

    const int tid = threadIdx.x;
    const int wid = tid >> 6;
    const int lane = tid & 63;
    const int wm = wid & 1, wn = wid >> 1;
    const int lm = lane & 15;
    const int lq = lane >> 4;

    const unsigned short* Ab = At + (size_t)mb * BLK_ELEMS;
    const unsigned short* Bb = Bt + (size_t)nb * BLK_ELEMS;

    f32x4 acc[4][4];
    #pragma unroll
    for (int i = 0; i < 4; ++i)
        #pragma unroll
        for (int j = 0; j < 4; ++j) acc[i][j] = (f32x4)0.f;

    for (int kt = 0; kt < 8; ++kt) {
        __syncthreads();
        const unsigned short* ga = Ab + kt * (8 * 1024);
        const unsigned short* gb = Bb + kt * (8 * 1024);
        #pragma unroll
        for (int i = 0; i < 4; ++i) {
            int off = (tid + i * 256) * 8;
            load_lds16(ga + off, As + off);
            load_lds16(gb + off, Bs + off);
        }
        __syncthreads();
        #pragma unroll
        for (int ks = 0; ks < 2; ++ks) {
            int g = ks * 4 + lq;
            int base = g * 1024 + lm * 8;
            short8 af[4], bfr[4];
            #pragma unroll
            for (int mt = 0; mt < 4; ++mt)
                af[mt] = *(const short8*)&As[base + (wm * 64 + mt * 16) * 8];
            #pragma unroll
            for (int nt = 0; nt < 4; ++nt)
                bfr[nt] = *(const short8*)&Bs[base + (wn * 64 + nt * 16) * 8];
            #pragma unroll
            for (int mt = 0; mt < 4; ++mt)
                #pragma unroll
                for (int nt = 0; nt < 4; ++nt)
                    acc[mt][nt] = __builtin_amdgcn_mfma_f32_16x16x32_bf16(
                        af[mt], bfr[nt], acc[mt][nt], 0, 0, 0);
        }
    }

    #pragma unroll
    for (int mt = 0; mt < 4; ++mt) {
        #pragma unroll
        for (int nt = 0; nt < 4; ++nt) {
            int col = nb * 128 + wn * 64 + nt * 16 + lm;
            f32x4 v = acc[mt][nt];
            #pragma unroll
            for (int r = 0; r < 4; ++r) {
                int row = mb * 128 + wm * 64 + mt * 16 + lq * 4 + r;
                if (row < M)
                    ((unsigned short*)Cout)[(size_t)row * HIDDEN + col] = f2bf(v[r]);
            }
        }
    }
}

// XCD-grouped swizzle: 4 nb blocks of one mb land on one XCD back-to-back
__device__ __forceinline__ bool swz_decode(int bid, int NB, int& mb, int& nb) {
    int p = bid & 7;
    int s = bid >> 3;
    nb = s & 3;
    mb = (s >> 2) * 8 + p;
    return mb < NB;
}

__global__ __launch_bounds__(256)
void gemm_swz(const unsigned short* __restrict__ At, const unsigned short* __restrict__ Bt,
              void* __restrict__ Cout, int M, int NB) {
    int mb, nb;
    if (!swz_decode(blockIdx.x, NB, mb, nb)) return;
    gemm_body(At, Bt, Cout, M, mb, nb);
}

// ---------------- fused: CSR fill | gemm layer-1 ----------------

__global__ __launch_bounds__(256)
void fused_fill_gemm1(const int* __restrict__ src, const int* __restrict__ dstv,
                      const float* __restrict__ norm, int* __restrict__ cursor,
                      int2* __restrict__ epair, int E, int fillB,
                      const unsigned short* __restrict__ At, const unsigned short* __restrict__ Bt,
                      void* __restrict__ Cout, int M, int NB) {
    int b = blockIdx.x;
    if (b < fillB) {
        int e = b * 256 + threadIdx.x;
        if (e < E) {
            int s = src[e], d = dstv[e];
            float cf = norm[s] * norm[d];
            int p = atomicAdd(&cursor[d], 1);
            epair[p] = make_int2(s, __float_as_int(cf));
        }
    } else {
        int mb, nb;
        if (swz_decode(b - fillB, NB, mb, nb))
            gemm_body(At, Bt, Cout, M, mb, nb);
    }
}

// ---------------- aggregation #1: wave-per-node, 16 waves/block (R0 proven form) ----
// BW pinned at 3.7-4.1 TB/s across 3 concurrency configs (R0-R2) -> structural
// floor for the random-1KB-gather mix. Known poison: launch_bounds min-waves
// (R2: acc spilled, WRITE 454MB); nontemporal store (R7: write-combining broken,
// WRITE 65->157MB, +52us); wave-serial epilogue (R6: 675us).

__global__ __launch_bounds__(1024)
void aggregate_kernel(const unsigned short* __restrict__ h, const int* __restrict__ rowptr,
                      const int2* __restrict__ epair, const float* __restrict__ norm,
                      const float* __restrict__ bias, unsigned short* __restrict__ out_t,
                      int N) {
    const int wave = threadIdx.x >> 6;
    const int lane = threadIdx.x & 63;
    const int node = blockIdx.x * 16 + wave;
    if (node >= N) return;
    const uint4* h4 = (const uint4*)h;   // 64 chunks of 16B per row
    const int c = lane;

    float a[8];
    {
        uint4 sv = h4[(size_t)node * 64 + c];
        float nv = norm[node];
        float invd = nv * nv;
        a[0] = a[1] = a[2] = a[3] = a[4] = a[5] = a[6] = a[7] = 0.f;
        acc8(sv, invd, a);
    }

    int beg = rowptr[node], end = rowptr[node + 1];
    int j = beg;
    for (; j + 4 <= end; j += 4) {
        int2 p0 = epair[j + 0];
        int2 p1 = epair[j + 1];
        int2 p2 = epair[j + 2];
        int2 p3 = epair[j + 3];
        uint4 v0 = h4[(size_t)p0.x * 64 + c];
        uint4 v1 = h4[(size_t)p1.x * 64 + c];
        uint4 v2 = h4[(size_t)p2.x * 64 + c];
        uint4 v3 = h4[(size_t)p3.x * 64 + c];
        acc8(v0, __int_as_float(p0.y), a);
        acc8(v1, __int_as_float(p1.y), a);
        acc8(v2, __int_as_float(p2.y), a);
        acc8(v3, __int_as_float(p3.y), a);
    }
    for (; j < end; ++j) {
        int2 p = epair[j];
        uint4 v = h4[(size_t)p.x * 64 + c];
        acc8(v, __int_as_float(p.y), a);
    }

    const float4 b0 = *(const float4*)(bias + c * 8);
    const float4 b1 = *(const float4*)(bias + c * 8 + 4);
    a[0] = fmaxf(a[0] + b0.x, 0.f); a[1] = fmaxf(a[1] + b0.y, 0.f);
    a[2] = fmaxf(a[2] + b0.z, 0.f); a[3] = fmaxf(a[3] + b0.w, 0.f);
    a[4] = fmaxf(a[4] + b1.x, 0.f); a[5] = fmaxf(a[5] + b1.y, 0.f);
    a[6] = fmaxf(a[6] + b1.z, 0.f); a[7] = fmaxf(a[7] + b1.w, 0.f);

    size_t off = (size_t)(node >> 7) * BLK_ELEMS + (size_t)c * 1024 + (node & 127) * 8;
    uint4 o;
    o.x = (unsigned)f2bf(a[0]) | ((unsigned)f2bf(a[1]) << 16);
    o.y = (unsigned)f2bf(a[2]) | ((unsigned)f2bf(a[3]) << 16);
    o.z = (unsigned)f2bf(a[4]) | ((unsigned)f2bf(a[5]) << 16);
    o.w = (unsigned)f2bf(a[6]) | ((unsigned)f2bf(a[7]) << 16);
    *(uint4*)(out_t + off) = o;
}

// ---------------- aggregation #2 + MFMA classifier (proven R8) ----------------

__global__ __launch_bounds__(1024)
void aggregate_cls_mfma(const unsigned short* __restrict__ h, const int* __restrict__ rowptr,
                        const int2* __restrict__ epair, const float* __restrict__ norm,
                        const float* __restrict__ bias, const unsigned short* __restrict__ Wct,
                        const float* __restrict__ bc, float* __restrict__ out,
                        int N, int NC) {
    __shared__ __align__(16) unsigned short h2s[16 * 520];
    const int wave = threadIdx.x >> 6;
    const int lane = threadIdx.x & 63;
    const int node = blockIdx.x * 16 + wave;
    const uint4* h4 = (const uint4*)h;
    const int c = lane;

    float a[8];
    a[0] = a[1] = a[2] = a[3] = a[4] = a[5] = a[6] = a[7] = 0.f;
    if (node < N) {
        {
            uint4 sv = h4[(size_t)node * 64 + c];
            float nv = norm[node];
            acc8(sv, nv * nv, a);
        }
        int beg = rowptr[node], end = rowptr[node + 1];
        int j = beg;
        for (; j + 4 <= end; j += 4) {
            int2 p0 = epair[j + 0];
            int2 p1 = epair[j + 1];
            int2 p2 = epair[j + 2];
            int2 p3 = epair[j + 3];
            uint4 v0 = h4[(size_t)p0.x * 64 + c];
            uint4 v1 = h4[(size_t)p1.x * 64 + c];
            uint4 v2 = h4[(size_t)p2.x * 64 + c];
            uint4 v3 = h4[(size_t)p3.x * 64 + c];
            acc8(v0, __int_as_float(p0.y), a);
            acc8(v1, __int_as_float(p1.y), a);
            acc8(v2, __int_as_float(p2.y), a);
            acc8(v3, __int_as_float(p3.y), a);
        }
        for (; j < end; ++j) {
            int2 p = epair[j];
            uint4 v = h4[(size_t)p.x * 64 + c];
            acc8(v, __int_as_float(p.y), a);
        }
        const float4 b0 = *(const float4*)(bias + c * 8);
        const float4 b1 = *(const float4*)(bias + c * 8 + 4);
        a[0] = fmaxf(a[0] + b0.x, 0.f); a[1] = fmaxf(a[1] + b0.y, 0.f);
        a[2] = fmaxf(a[2] + b0.z, 0.f); a[3] = fmaxf(a[3] + b0.w, 0.f);
        a[4] = fmaxf(a[4] + b1.x, 0.f); a[5] = fmaxf(a[5] + b1.y, 0.f);
        a[6] = fmaxf(a[6] + b1.z, 0.f); a[7] = fmaxf(a[7] + b1.w, 0.f);
    }

    {
        short8 v;
        v[0] = (short)f2bf(a[0]); v[1] = (short)f2bf(a[1]);
        v[2] = (short)f2bf(a[2]); v[3] = (short)f2bf(a[3]);
        v[4] = (short)f2bf(a[4]); v[5] = (short)f2bf(a[5]);
        v[6] = (short)f2bf(a[6]); v[7] = (short)f2bf(a[7]);
        *(short8*)(h2s + wave * 520 + c * 8) = v;
    }
    __syncthreads();

    const int ct = wave;
    if (ct * 16 < NC) {
        const int lm = lane & 15;
        const int lq = lane >> 4;
        f32x4 acc = (f32x4)0.f;
        #pragma unroll
        for (int kk = 0; kk < 16; ++kk) {
            int g = kk * 4 + lq;                         // 8-elem k-chunk, 0..63
            short8 af = *(const short8*)&h2s[lm * 520 + g * 8];
            short8 bf = *(const short8*)&Wct[(size_t)g * 1024 + (ct * 16 + lm) * 8];
            acc = __builtin_amdgcn_mfma_f32_16x16x32_bf16(af, bf, acc, 0, 0, 0);
        }
        int col = ct * 16 + lm;
        if (col < NC) {
            float bcv = bc[col];
            #pragma unroll
            for (int r = 0; r < 4; ++r) {
                int row = lq * 4 + r;
                int gnode = blockIdx.x * 16 + row;
                if (gnode < N)
                    out[(size_t)gnode * NC + col] = acc[r] + bcv;
            }
        }
    }
}

// ---------------- launch ----------------
// R12: exact revert to the R8 configuration (best verified: 467.8us).
// R11's scan merge regressed +17us (latency-chain prefix sum); launch gaps are
// only ~2-5us (R10 measurement), so the two-kernel bsums handshake stays.

extern "C" void kernel_launch(void* const* d_in, const int* in_sizes, int n_in,
                              void* d_out, int out_size, void* d_ws, size_t ws_size,
                              hipStream_t stream) {
    const float* x  = (const float*)d_in[0];
    const int*   ei = (const int*)d_in[1];
    const float* W1 = (const float*)d_in[2];
    const float* b1 = (const float*)d_in[3];
    const float* W2 = (const float*)d_in[4];
    const float* b2 = (const float*)d_in[5];
    const float* Wc = (const float*)d_in[6];
    const float* bc = (const float*)d_in[7];

    const int N  = in_sizes[0] / HIDDEN;      // 50000
    const int E  = in_sizes[1] / 2;           // 500000
    const int NC = in_sizes[6] / HIDDEN;      // 100
    const int NB = (N + 127) / 128;           // 391
    const int NSB = (N + 255) / 256;          // 196

    const int* src = ei;
    const int* dst = ei + E;

    char* ws = (char*)d_ws;
    int*   cnt    = (int*)(ws);
    int*   rowptr = (int*)(ws + (256 << 10));
    int*   cursor = (int*)(ws + (512 << 10));
    float* normv  = (float*)(ws + (768 << 10));
    int*   bsums  = (int*)(ws + (968 << 10));
    int2*  epair  = (int2*)(ws + (1ull << 20));                 // E*8 B = 4 MB
    unsigned short* W1t = (unsigned short*)(ws + (6ull << 20));
    unsigned short* W2t = (unsigned short*)(ws + (6ull << 20) + (512 << 10));
    unsigned short* Wct = (unsigned short*)(ws + (7ull << 20));
    unsigned short* bufA = (unsigned short*)(ws + (16ull << 20));
    unsigned short* bufB = (unsigned short*)(ws + (80ull << 20));
    unsigned short* hbuf = (unsigned short*)(ws + (144ull << 20));

    const int countB = (E + 255) / 256;                 // 1954
    const int nxb = NB * 4;                             // 1564 castx blocks (32 rows each)
    const int gemmB = 8 * 4 * ((NB + 7) / 8);           // 1568

    hipMemsetAsync(cnt, 0, N * sizeof(int), stream);
    // [edge count | cast x (block-transpose)]
    fused_count_castx<<<countB + nxb, 256, 0, stream>>>(dst, cnt, E, countB,
                                                        x, bufA, N, nxb);
    // [block sums + norm | cast W1/W2/Wc]
    fused_bsum_castw<<<NSB + 288, 256, 0, stream>>>(cnt, normv, bsums, N, NSB,
                                                    W1, W2, Wc, W1t, W2t, Wct, NC);
    // merged block-offset + element scan (bsums rescan, 1 iteration per block)
    scan_final_kernel<<<NSB, 256, 0, stream>>>(cnt, bsums, rowptr, cursor, N, NSB);
    // [CSR fill | gemm layer-1]
    fused_fill_gemm1<<<countB + gemmB, 256, 0, stream>>>(src, dst, normv, cursor, epair,
                                                         E, countB,
                                                         bufA, W1t, hbuf, N, NB);
    const int aggB = (N + 15) / 16;
    aggregate_kernel<<<aggB, 1024, 0, stream>>>(hbuf, rowptr, epair, normv, b1, bufB, N);
    gemm_swz<<<gemmB, 256, 0, stream>>>(bufB, W2t, hbuf, N, NB);
    // [aggregation 2 + MFMA classifier] -> d_out directly
    aggregate_cls_mfma<<<aggB, 1024, 0, stream>>>(hbuf, rowptr, epair, normv, b2,
                                                  Wct, bc, (float*)d_out, N, NC);
}